// Round 14
// baseline (257.175 us; speedup 1.0000x reference)
//
#include <hip/hip_runtime.h>
#include <math.h>

// ---------------------------------------------------------------------------
// SAINT-style 2-layer graph conv + linear head + log_softmax
// N=100000 nodes, E=1600000 edges, C=64, HID=64, OUT=40
// Round 13: revert to round-9 structure (best: 225us). spmm -> 32 lanes/node
//           (two 16-lane halves own alternating 8-edge blocks; shfl_xor(16)
//           merge) to halve the per-lane serial gather chain.
// ---------------------------------------------------------------------------

typedef unsigned short u16;
typedef unsigned int   u32;

#define BROWS 512
#define BIN_CHUNK 8192
#define CAPB 12288         // per-bucket capacity clamp

__device__ __forceinline__ u16 f2bf(float f) {
  u32 u = __float_as_uint(f);
  u32 r = u + 0x7fffu + ((u >> 16) & 1u);
  return (u16)(r >> 16);
}
__device__ __forceinline__ float bf2f(u16 h) {
  return __uint_as_float(((u32)h) << 16);
}

// ---- pass A: bin edges into NB bucket regions, packed (lrow<<17)|col -------
__global__ __launch_bounds__(1024) void k_binA(
    const int* __restrict__ row, const int* __restrict__ col,
    unsigned* __restrict__ bCnt, unsigned* __restrict__ pairs,
    int nE, int NB, int capA)
{
  __shared__ unsigned buf[BIN_CHUNK];
  __shared__ unsigned cnt[16][256];
  __shared__ unsigned base[256], gb[256], tot[256], sc[256];
  const int t = threadIdx.x;
  const int wave = t >> 6, lane = t & 63;
  const int tb = blockIdx.x * BIN_CHUNK;

  for (int i = t; i < 16 * 256; i += 1024) ((unsigned*)cnt)[i] = 0;
  __syncthreads();

  unsigned pk[8];
  unsigned short po[8];
  short bk[8];
#pragma unroll
  for (int j = 0; j < 8; ++j) {
    int i = tb + j * 1024 + t;
    if (i < nE) {
      int r = row[i], c = col[i];
      int b = r >> 9;
      pk[j] = ((unsigned)(r & (BROWS - 1)) << 17) | (unsigned)c;
      bk[j] = (short)b;
      po[j] = (unsigned short)atomicAdd(&cnt[wave][b], 1u);
    } else bk[j] = -1;
  }
  __syncthreads();

  if (t < 256) {
    unsigned run = 0;
#pragma unroll
    for (int w = 0; w < 16; ++w) {
      unsigned c = cnt[w][t];
      cnt[w][t] = run;
      run += c;
    }
    tot[t] = run;
    sc[t] = run;
  }
  __syncthreads();
  for (int off = 1; off < 256; off <<= 1) {
    unsigned v = 0;
    if (t < 256 && t >= off) v = sc[t - off];
    __syncthreads();
    if (t < 256) sc[t] += v;
    __syncthreads();
  }
  if (t < 256) {
    base[t] = t ? sc[t - 1] : 0u;
    unsigned c = tot[t];
    gb[t] = c ? atomicAdd(&bCnt[t], c) : 0u;
  }
  __syncthreads();

#pragma unroll
  for (int j = 0; j < 8; ++j)
    if (bk[j] >= 0) buf[base[bk[j]] + cnt[wave][bk[j]] + po[j]] = pk[j];
  __syncthreads();

  for (int b = wave; b < NB; b += 16) {
    unsigned cb = tot[b];
    if (!cb) continue;
    unsigned lo = base[b], g = gb[b];
    size_t dst = (size_t)b * (unsigned)capA;
    for (unsigned u = lane; u < cb; u += 64)
      if (g + u < (unsigned)capA) pairs[dst + g + u] = buf[lo + u];
  }
}

__global__ __launch_bounds__(256) void k_bscan(const unsigned* __restrict__ bCnt,
                                               unsigned* __restrict__ bBase, int NB) {
  __shared__ unsigned sc[256];
  int t = threadIdx.x;
  unsigned v = (t < NB) ? min(bCnt[t], (unsigned)CAPB) : 0u;
  sc[t] = v;
  __syncthreads();
  for (int off = 1; off < 256; off <<= 1) {
    unsigned u = (t >= off) ? sc[t - off] : 0u;
    __syncthreads();
    sc[t] += u;
    __syncthreads();
  }
  if (t < NB) bBase[t] = t ? sc[t - 1] : 0u;
}

// ---- pass B: per-bucket local CSR; 512 threads = 1 thread per local row ----
__global__ __launch_bounds__(512) void k_binB(
    const unsigned* __restrict__ pairs, const unsigned* __restrict__ bCnt,
    const unsigned* __restrict__ bBase, int* __restrict__ colS,
    unsigned* __restrict__ start, float* __restrict__ dis,
    int N, int capA)
{
  __shared__ unsigned hist[BROWS], cur[BROWS], sc[BROWS];
  __shared__ unsigned cols[CAPB];
  const int t = threadIdx.x;
  const int b = blockIdx.x;
  const unsigned cnt = min(bCnt[b], (unsigned)CAPB);
  const unsigned gbase = bBase[b];
  const size_t src = (size_t)b * (unsigned)capA;

  hist[t] = 0;
  __syncthreads();
  for (unsigned i = t; i < cnt; i += 512)
    atomicAdd(&hist[pairs[src + i] >> 17], 1u);
  __syncthreads();
  const unsigned h = hist[t];
  sc[t] = h;
  __syncthreads();
  for (int off = 1; off < 512; off <<= 1) {
    unsigned v = (t >= off) ? sc[t - off] : 0u;
    __syncthreads();
    sc[t] += v;
    __syncthreads();
  }
  const unsigned e = sc[t] - h;
  cur[t] = e;
  __syncthreads();
  for (unsigned i = t; i < cnt; i += 512) {
    unsigned p = pairs[src + i];
    unsigned pos = atomicAdd(&cur[p >> 17], 1u);
    cols[pos] = p & 0x1FFFFu;
  }
  __syncthreads();
  for (unsigned i = t; i < cnt; i += 512)
    colS[gbase + i] = (int)cols[i];
  const int n = b * BROWS + t;
  if (n < N) {
    start[n] = gbase + e + h;       // segment END offset
    dis[n] = h ? rsqrtf((float)h) : 0.f;
  }
}

// ---------------- fallback-path CSR build -----------------------------------
__global__ __launch_bounds__(256) void k_deg(const int* __restrict__ row,
                                             unsigned* __restrict__ deg, int nE) {
  int i = blockIdx.x * blockDim.x + threadIdx.x;
  int stride = gridDim.x * blockDim.x;
  for (; i < nE; i += stride) atomicAdd(&deg[row[i]], 1u);
}

__global__ __launch_bounds__(256) void k_dis(const unsigned* __restrict__ deg,
                                             float* __restrict__ dis, int n) {
  int i = blockIdx.x * blockDim.x + threadIdx.x;
  if (i < n) {
    unsigned d = deg[i];
    dis[i] = d > 0u ? rsqrtf((float)d) : 0.f;
  }
}

__global__ __launch_bounds__(256) void k_scan1(const unsigned* __restrict__ deg,
                                               unsigned* __restrict__ start,
                                               unsigned* __restrict__ bsum, int n) {
  __shared__ unsigned s[256];
  const int base = blockIdx.x * 2048;
  unsigned v[8], tsum = 0;
#pragma unroll
  for (int j = 0; j < 8; ++j) {
    int idx = base + threadIdx.x * 8 + j;
    v[j] = idx < n ? deg[idx] : 0u;
    tsum += v[j];
  }
  s[threadIdx.x] = tsum;
  __syncthreads();
  for (int off = 1; off < 256; off <<= 1) {
    unsigned t = (threadIdx.x >= off) ? s[threadIdx.x - off] : 0u;
    __syncthreads();
    s[threadIdx.x] += t;
    __syncthreads();
  }
  unsigned run = threadIdx.x ? s[threadIdx.x - 1] : 0u;
  if (threadIdx.x == 255) bsum[blockIdx.x] = s[255];
#pragma unroll
  for (int j = 0; j < 8; ++j) {
    int idx = base + threadIdx.x * 8 + j;
    if (idx < n) start[idx] = run;
    run += v[j];
  }
}

__global__ void k_scan2(unsigned* __restrict__ bsum, int nB) {
  if (threadIdx.x == 0 && blockIdx.x == 0) {
    unsigned run = 0;
    for (int b = 0; b < nB; ++b) { unsigned t = bsum[b]; bsum[b] = run; run += t; }
  }
}

__global__ __launch_bounds__(256) void k_scan3(unsigned* __restrict__ start,
                                               const unsigned* __restrict__ bsum, int n) {
  int i = blockIdx.x * blockDim.x + threadIdx.x;
  if (i < n) start[i] += bsum[i >> 11];
}

__global__ __launch_bounds__(256) void k_build(const int* __restrict__ row,
                                               const int* __restrict__ col,
                                               unsigned* __restrict__ start,
                                               int* __restrict__ colS, int nE) {
  int i = blockIdx.x * blockDim.x + threadIdx.x;
  int stride = gridDim.x * blockDim.x;
  for (; i < nE; i += stride) {
    int r = row[i];
    unsigned p = atomicAdd(&start[r], 1u);
    colS[p] = col[i];
  }
}

// ---------------- edge records + rs (once; layer-invariant) -----------------
__global__ __launch_bounds__(256) void k_wgt(
    const int* __restrict__ colS, const unsigned* __restrict__ startEnd,
    const float* __restrict__ dis, uint2* __restrict__ rec,
    float* __restrict__ rs, int nNodes)
{
  const int t = threadIdx.x;
  const int sub = t & 15;
  const int n = blockIdx.x * 16 + (t >> 4);
  if (n >= nNodes) return;
  const unsigned lo = n ? startEnd[n - 1] : 0u;
  const unsigned hi = startEnd[n];
  float s = 0.f;
  for (unsigned u = lo + sub; u < hi; u += 16) {
    int c = colS[u];
    float w = dis[c];
    rec[u] = make_uint2((unsigned)c, __float_as_uint(w));
    s += w;
  }
  s += __shfl_xor(s, 1); s += __shfl_xor(s, 2);
  s += __shfl_xor(s, 4); s += __shfl_xor(s, 8);
  if (sub == 0) rs[n] = dis[n] * s;
}

// ---------------- f32 -> bf16 cast ------------------------------------------
__global__ __launch_bounds__(256) void k_cast(const float4* __restrict__ x4,
                                              ushort4* __restrict__ out, int n4) {
  int i = blockIdx.x * blockDim.x + threadIdx.x;
  int stride = gridDim.x * blockDim.x;
  for (; i < n4; i += stride) {
    float4 f = x4[i];
    ushort4 v;
    v.x = f2bf(f.x); v.y = f2bf(f.y); v.z = f2bf(f.z); v.w = f2bf(f.w);
    out[i] = v;
  }
}

// ---------------- weight prep: UT[layer][kq][o] -----------------------------
__global__ __launch_bounds__(256) void k_prep(
    const float* __restrict__ W1, const float* __restrict__ b1,
    const float* __restrict__ Wr1, const float* __restrict__ br1,
    const float* __restrict__ W2, const float* __restrict__ b2,
    const float* __restrict__ Wr2, const float* __restrict__ br2,
    float4* __restrict__ UT)
{
  int i = blockIdx.x * 256 + threadIdx.x;
  if (i >= 2 * 33 * 64) return;
  int layer = i / (33 * 64);
  int kq = (i / 64) % 33;
  int o = i % 64;
  const float* W  = layer ? W2  : W1;
  const float* Wr = layer ? Wr2 : Wr1;
  const float* b  = layer ? b2  : b1;
  const float* br = layer ? br2 : br1;
  float4 v;
  if (kq < 16)       v = ((const float4*)W)[o * 16 + kq];
  else if (kq < 32)  v = ((const float4*)Wr)[o * 16 + kq - 16];
  else               v = make_float4(b[o], br[o], 0.f, 0.f);
  UT[i] = v;
}

// ---------------- spmm: aggh[n,:] = bf16(dis[n]*sum w_e*x[c_e,:]) -----------
// 32 lanes per node (2 nodes/wave): feature sub = lane&15; the two 16-lane
// halves own alternating 8-edge blocks -> per-lane serial chain halves.
// Merge via shfl_xor(16). Reassociation is within bf16 tolerance.
__global__ __launch_bounds__(256) void k_spmm_rec(
    const u16* __restrict__ xh, u16* __restrict__ aggh,
    const uint2* __restrict__ rec, const unsigned* __restrict__ startEnd,
    const float* __restrict__ dis, int nNodes)
{
  const int t = threadIdx.x;
  const int sub = t & 15;
  const unsigned half = (t >> 4) & 1;
  const int n = blockIdx.x * 8 + (t >> 5);
  if (n >= nNodes) return;
  const unsigned lo = n ? startEnd[n - 1] : 0u;
  const unsigned hi = startEnd[n];
  const ushort4* h4 = (const ushort4*)xh;

  float ax = 0.f, ay = 0.f, az = 0.f, aw = 0.f;
  const unsigned nb = (hi - lo) >> 3;          // full 8-edge blocks
  unsigned p = lo + half * 8;
  for (unsigned b = half; b < nb; b += 2, p += 16) {
    uint2 r0 = rec[p],     r1 = rec[p + 1];
    uint2 r2 = rec[p + 2], r3 = rec[p + 3];
    uint2 r4 = rec[p + 4], r5 = rec[p + 5];
    uint2 r6 = rec[p + 6], r7 = rec[p + 7];
    ushort4 v0 = h4[(size_t)r0.x * 16 + sub];
    ushort4 v1 = h4[(size_t)r1.x * 16 + sub];
    ushort4 v2 = h4[(size_t)r2.x * 16 + sub];
    ushort4 v3 = h4[(size_t)r3.x * 16 + sub];
    ushort4 v4 = h4[(size_t)r4.x * 16 + sub];
    ushort4 v5 = h4[(size_t)r5.x * 16 + sub];
    ushort4 v6 = h4[(size_t)r6.x * 16 + sub];
    ushort4 v7 = h4[(size_t)r7.x * 16 + sub];
    float w0 = __uint_as_float(r0.y), w1 = __uint_as_float(r1.y);
    float w2 = __uint_as_float(r2.y), w3 = __uint_as_float(r3.y);
    float w4 = __uint_as_float(r4.y), w5 = __uint_as_float(r5.y);
    float w6 = __uint_as_float(r6.y), w7 = __uint_as_float(r7.y);
    ax += w0 * bf2f(v0.x) + w1 * bf2f(v1.x) + w2 * bf2f(v2.x) + w3 * bf2f(v3.x);
    ay += w0 * bf2f(v0.y) + w1 * bf2f(v1.y) + w2 * bf2f(v2.y) + w3 * bf2f(v3.y);
    az += w0 * bf2f(v0.z) + w1 * bf2f(v1.z) + w2 * bf2f(v2.z) + w3 * bf2f(v3.z);
    aw += w0 * bf2f(v0.w) + w1 * bf2f(v1.w) + w2 * bf2f(v2.w) + w3 * bf2f(v3.w);
    ax += w4 * bf2f(v4.x) + w5 * bf2f(v5.x) + w6 * bf2f(v6.x) + w7 * bf2f(v7.x);
    ay += w4 * bf2f(v4.y) + w5 * bf2f(v5.y) + w6 * bf2f(v6.y) + w7 * bf2f(v7.y);
    az += w4 * bf2f(v4.z) + w5 * bf2f(v5.z) + w6 * bf2f(v6.z) + w7 * bf2f(v7.z);
    aw += w4 * bf2f(v4.w) + w5 * bf2f(v5.w) + w6 * bf2f(v6.w) + w7 * bf2f(v7.w);
  }
  // partial tail block (index nb) belongs to half nb&1
  if ((nb & 1u) == half) {
    for (unsigned q = lo + nb * 8; q < hi; ++q) {
      uint2 r = rec[q];
      ushort4 v = h4[(size_t)r.x * 16 + sub];
      float w = __uint_as_float(r.y);
      ax += w * bf2f(v.x); ay += w * bf2f(v.y);
      az += w * bf2f(v.z); aw += w * bf2f(v.w);
    }
  }
  // merge the two halves (lane ^ 16)
  ax += __shfl_xor(ax, 16); ay += __shfl_xor(ay, 16);
  az += __shfl_xor(az, 16); aw += __shfl_xor(aw, 16);
  if (half == 0) {
    const float dn = dis[n];
    ushort4 o;
    o.x = f2bf(dn * ax); o.y = f2bf(dn * ay);
    o.z = f2bf(dn * az); o.w = f2bf(dn * aw);
    ((ushort4*)aggh)[(size_t)n * 16 + sub] = o;
  }
}

// ---------------- gemv: x_out = relu(agg@W^T + rs*b + root@Wr^T + br) -------
__global__ __launch_bounds__(256) void k_gemv(
    const u16* __restrict__ aggh, const float* __restrict__ rs,
    const u16* __restrict__ rooth, const float4* __restrict__ UT,
    u16* __restrict__ xo, int nNodes)
{
  __shared__ u16 xsh[64][136];
  const int t = threadIdx.x;
  const int lane = t & 63;
  const int og = __builtin_amdgcn_readfirstlane(t >> 6);
  const int n0 = blockIdx.x * 64;

  {
    const int r = t >> 2, q = t & 3;
    int gn = n0 + r; if (gn > nNodes - 1) gn = nNodes - 1;
    const uint4* a = (const uint4*)(aggh + (size_t)gn * 64);
    const uint4* x = (const uint4*)(rooth + (size_t)gn * 64);
    *(uint4*)&xsh[r][q * 16]           = a[q * 2];
    *(uint4*)&xsh[r][q * 16 + 8]       = a[q * 2 + 1];
    *(uint4*)&xsh[r][64 + q * 16]      = x[q * 2];
    *(uint4*)&xsh[r][64 + q * 16 + 8]  = x[q * 2 + 1];
  }
  __syncthreads();

  float acc[16];
#pragma unroll
  for (int j = 0; j < 16; ++j) acc[j] = 0.f;

#pragma unroll 4
  for (int k = 0; k < 32; ++k) {
    ushort4 v = *(const ushort4*)&xsh[lane][k * 4];
    float xa = bf2f(v.x), xb = bf2f(v.y), xc = bf2f(v.z), xd = bf2f(v.w);
    const float4* w = UT + k * 64 + og * 16;
#pragma unroll
    for (int j = 0; j < 16; ++j) {
      float4 W = w[j];
      acc[j] = fmaf(xa, W.x, fmaf(xb, W.y, fmaf(xc, W.z, fmaf(xd, W.w, acc[j]))));
    }
  }

  const int n = n0 + lane;
  const float rsv = (n < nNodes) ? rs[n] : 0.f;
  {
    const float4* w = UT + 32 * 64 + og * 16;
#pragma unroll
    for (int j = 0; j < 16; ++j) {
      float4 W = w[j];
      acc[j] = fmaf(rsv, W.x, acc[j]) + W.y;
    }
  }

  if (n < nNodes) {
    uint4 u0, u1;
    u0.x = (u32)f2bf(fmaxf(acc[0], 0.f))  | ((u32)f2bf(fmaxf(acc[1], 0.f)) << 16);
    u0.y = (u32)f2bf(fmaxf(acc[2], 0.f))  | ((u32)f2bf(fmaxf(acc[3], 0.f)) << 16);
    u0.z = (u32)f2bf(fmaxf(acc[4], 0.f))  | ((u32)f2bf(fmaxf(acc[5], 0.f)) << 16);
    u0.w = (u32)f2bf(fmaxf(acc[6], 0.f))  | ((u32)f2bf(fmaxf(acc[7], 0.f)) << 16);
    u1.x = (u32)f2bf(fmaxf(acc[8], 0.f))  | ((u32)f2bf(fmaxf(acc[9], 0.f)) << 16);
    u1.y = (u32)f2bf(fmaxf(acc[10], 0.f)) | ((u32)f2bf(fmaxf(acc[11], 0.f)) << 16);
    u1.z = (u32)f2bf(fmaxf(acc[12], 0.f)) | ((u32)f2bf(fmaxf(acc[13], 0.f)) << 16);
    u1.w = (u32)f2bf(fmaxf(acc[14], 0.f)) | ((u32)f2bf(fmaxf(acc[15], 0.f)) << 16);
    uint4* dst = (uint4*)(xo + (size_t)n * 64 + og * 16);
    dst[0] = u0;
    dst[1] = u1;
  }
}

// ---------------- head: log_softmax(concat(x1,x2)@Wl^T + bl) ----------------
__global__ __launch_bounds__(256) void k_final(
    const u16* __restrict__ x1h, const u16* __restrict__ x2h,
    const float* __restrict__ Wl, const float* __restrict__ bl,
    float* __restrict__ out, int nNodes)
{
  __shared__ float4 xs[64][33];
  __shared__ float redM[64][4];
  __shared__ float redS[64][4];
  const int t = threadIdx.x;
  const int lane = t & 63;
  const int og = __builtin_amdgcn_readfirstlane(t >> 6);
  const int nodeBase = blockIdx.x * 64;

  {
    const int sn = t >> 2, q = t & 3;
    int gn = nodeBase + sn;
    if (gn > nNodes - 1) gn = nNodes - 1;
    const ushort4* a = (q < 2) ? (const ushort4*)(x1h + (size_t)gn * 64)
                               : (const ushort4*)(x2h + (size_t)gn * 64);
    const int qq = q & 1;
#pragma unroll
    for (int j = 0; j < 8; ++j) {
      ushort4 v = a[qq * 8 + j];
      xs[sn][q * 8 + j] = make_float4(bf2f(v.x), bf2f(v.y), bf2f(v.z), bf2f(v.w));
    }
  }
  __syncthreads();

  const float4* W4 = (const float4*)Wl;
  float acc[10];
#pragma unroll
  for (int j = 0; j < 10; ++j) acc[j] = bl[og * 10 + j];
  for (int k = 0; k < 32; ++k) {
    float4 x = xs[lane][k];
#pragma unroll
    for (int j = 0; j < 10; ++j) {
      float4 w = W4[(og * 10 + j) * 32 + k];
      acc[j] += w.x * x.x + w.y * x.y + w.z * x.z + w.w * x.w;
    }
  }

  float m10 = acc[0];
#pragma unroll
  for (int j = 1; j < 10; ++j) m10 = fmaxf(m10, acc[j]);
  redM[lane][og] = m10;
  __syncthreads();
  float M = fmaxf(fmaxf(redM[lane][0], redM[lane][1]),
                  fmaxf(redM[lane][2], redM[lane][3]));
  float s10 = 0.f;
#pragma unroll
  for (int j = 0; j < 10; ++j) s10 += __expf(acc[j] - M);
  redS[lane][og] = s10;
  __syncthreads();
  const float S = redS[lane][0] + redS[lane][1] + redS[lane][2] + redS[lane][3];
  const float lse = M + __logf(S);

  const int n = nodeBase + lane;
  if (n < nNodes) {
    float2* o2 = (float2*)(out + (size_t)n * 40 + og * 10);
#pragma unroll
    for (int q = 0; q < 5; ++q)
      o2[q] = make_float2(acc[2 * q] - lse, acc[2 * q + 1] - lse);
  }
}

extern "C" void kernel_launch(void* const* d_in, const int* in_sizes, int n_in,
                              void* d_out, int out_size, void* d_ws, size_t ws_size,
                              hipStream_t stream) {
  const float* x0  = (const float*)d_in[0];
  const int*   ei  = (const int*)d_in[1];
  const float* W1  = (const float*)d_in[2];
  const float* b1  = (const float*)d_in[3];
  const float* Wr1 = (const float*)d_in[4];
  const float* br1 = (const float*)d_in[5];
  const float* W2  = (const float*)d_in[6];
  const float* b2  = (const float*)d_in[7];
  const float* Wr2 = (const float*)d_in[8];
  const float* br2 = (const float*)d_in[9];
  const float* Wl  = (const float*)d_in[10];
  const float* bl  = (const float*)d_in[11];
  float* out = (float*)d_out;

  const int N = in_sizes[0] / 64;
  const int E = in_sizes[1] / 2;
  const int* row = ei;
  const int* col = ei + E;

  const int NB = (N + BROWS - 1) / BROWS;
  const int capA = 16384;
  const int avg = E / (NB > 0 ? NB : 1);
  const bool binOK = (N <= 131072) && (NB <= 256) &&
                     (avg + 12 * (int)sqrtf((float)avg + 1.f) + 256 <= CAPB);

  size_t P = (size_t)NB * capA;
  if (P < (size_t)32 * N) P = (size_t)32 * N;

  const size_t UT_W = 2 * 33 * 64 * 4;  // words
  // bin: bCnt256|bBase256|P|colS E|rec 2E|start N|dis N|rs N|UT|aggh 32N|x1h 32N
  const size_t needBin = 4 * (512 + P + (size_t)3 * E + (size_t)3 * N + UT_W +
                              (size_t)32 * N + (size_t)32 * N);
  // csr: deg N|start N|dis N|rs N|bsum64|colS E|rec 2E|UT|aggh 32N|x1h 32N|xsh 32N
  const size_t needCSR = 4 * ((size_t)4 * N + 64 + (size_t)3 * E + UT_W +
                              (size_t)32 * N + (size_t)32 * N + (size_t)32 * N);

  unsigned *start = nullptr; float *dis = nullptr, *rsv = nullptr;
  int* colS = nullptr; uint2* rec = nullptr; float4* UT = nullptr;
  u16 *aggh = nullptr, *x0h = nullptr, *x1h = nullptr, *x2h = nullptr;
  bool ok = false;

  if (binOK && ws_size >= needBin) {
    unsigned* bCnt  = (unsigned*)d_ws;
    unsigned* bBase = bCnt + 256;
    unsigned* pairs = bBase + 256;
    colS  = (int*)(pairs + P);
    rec   = (uint2*)(colS + E);
    start = (unsigned*)(rec + E);
    dis   = (float*)(start + N);
    rsv   = dis + N;
    UT    = (float4*)(rsv + N);
    aggh  = (u16*)(UT + 2 * 33 * 64);
    x1h   = aggh + (size_t)64 * N;
    x0h   = (u16*)pairs;
    x2h   = (u16*)pairs;

    hipMemsetAsync(bCnt, 0, 256 * 4, stream);
    k_binA<<<(E + BIN_CHUNK - 1) / BIN_CHUNK, 1024, 0, stream>>>(row, col, bCnt, pairs, E, NB, capA);
    k_bscan<<<1, 256, 0, stream>>>(bCnt, bBase, NB);
    k_binB<<<NB, 512, 0, stream>>>(pairs, bCnt, bBase, colS, start, dis, N, capA);
    ok = true;
  } else if (ws_size >= needCSR) {
    unsigned* deg = (unsigned*)d_ws;
    start = deg + N;                 // becomes segment-END after k_build
    dis   = (float*)(start + N);
    rsv   = dis + N;
    unsigned* bsum = (unsigned*)(rsv + N);
    colS  = (int*)(bsum + 64);
    rec   = (uint2*)(colS + E);
    UT    = (float4*)(rec + E);
    aggh  = (u16*)(UT + 2 * 33 * 64);
    x1h   = aggh + (size_t)64 * N;
    u16* xsh = x1h + (size_t)64 * N;
    x0h = xsh; x2h = xsh;

    const int nB = (N + 2047) / 2048;
    hipMemsetAsync(deg, 0, (size_t)N * 4, stream);
    k_deg<<<1024, 256, 0, stream>>>(row, deg, E);
    k_dis<<<(N + 255) / 256, 256, 0, stream>>>(deg, dis, N);
    k_scan1<<<nB, 256, 0, stream>>>(deg, start, bsum, N);
    k_scan2<<<1, 64, 0, stream>>>(bsum, nB);
    k_scan3<<<(N + 255) / 256, 256, 0, stream>>>(start, bsum, N);
    k_build<<<1024, 256, 0, stream>>>(row, col, start, colS, E);
    ok = true;
  }

  if (!ok) return;

  k_wgt<<<(N + 15) / 16, 256, 0, stream>>>(colS, start, dis, rec, rsv, N);
  k_cast<<<1024, 256, 0, stream>>>((const float4*)x0, (ushort4*)x0h, N * 16);
  k_prep<<<17, 256, 0, stream>>>(W1, b1, Wr1, br1, W2, b2, Wr2, br2, UT);

  // layer 1
  k_spmm_rec<<<(N + 7) / 8, 256, 0, stream>>>(x0h, aggh, rec, start, dis, N);
  k_gemv<<<(N + 63) / 64, 256, 0, stream>>>(aggh, rsv, x0h, UT, x1h, N);

  // layer 2
  k_spmm_rec<<<(N + 7) / 8, 256, 0, stream>>>(x1h, aggh, rec, start, dis, N);
  k_gemv<<<(N + 63) / 64, 256, 0, stream>>>(aggh, rsv, x1h, UT + 33 * 64, x2h, N);

  // head
  k_final<<<(N + 63) / 64, 256, 0, stream>>>(x1h, x2h, Wl, bl, out, N);
}

// Round 15
// 239.889 us; speedup vs baseline: 1.0721x; 1.0721x over previous
//
#include <hip/hip_runtime.h>
#include <math.h>

// ---------------------------------------------------------------------------
// SAINT-style 2-layer graph conv + linear head + log_softmax
// N=100000 nodes, E=1600000 edges, C=64, HID=64, OUT=40
// Round 14: revert half-split (regression). spmm = round-9 structure with
//           dual-node interleave: each 16-lane group owns nodes 2g,2g+1
//           (contiguous CSR ranges); main loop interleaves 4 edges of each
//           -> 8 independent gathers in flight, no cross-lane merges.
// ---------------------------------------------------------------------------

typedef unsigned short u16;
typedef unsigned int   u32;

#define BROWS 512
#define BIN_CHUNK 8192
#define CAPB 12288         // per-bucket capacity clamp

__device__ __forceinline__ u16 f2bf(float f) {
  u32 u = __float_as_uint(f);
  u32 r = u + 0x7fffu + ((u >> 16) & 1u);
  return (u16)(r >> 16);
}
__device__ __forceinline__ float bf2f(u16 h) {
  return __uint_as_float(((u32)h) << 16);
}

// ---- pass A: bin edges into NB bucket regions, packed (lrow<<17)|col -------
__global__ __launch_bounds__(1024) void k_binA(
    const int* __restrict__ row, const int* __restrict__ col,
    unsigned* __restrict__ bCnt, unsigned* __restrict__ pairs,
    int nE, int NB, int capA)
{
  __shared__ unsigned buf[BIN_CHUNK];
  __shared__ unsigned cnt[16][256];
  __shared__ unsigned base[256], gb[256], tot[256], sc[256];
  const int t = threadIdx.x;
  const int wave = t >> 6, lane = t & 63;
  const int tb = blockIdx.x * BIN_CHUNK;

  for (int i = t; i < 16 * 256; i += 1024) ((unsigned*)cnt)[i] = 0;
  __syncthreads();

  unsigned pk[8];
  unsigned short po[8];
  short bk[8];
#pragma unroll
  for (int j = 0; j < 8; ++j) {
    int i = tb + j * 1024 + t;
    if (i < nE) {
      int r = row[i], c = col[i];
      int b = r >> 9;
      pk[j] = ((unsigned)(r & (BROWS - 1)) << 17) | (unsigned)c;
      bk[j] = (short)b;
      po[j] = (unsigned short)atomicAdd(&cnt[wave][b], 1u);
    } else bk[j] = -1;
  }
  __syncthreads();

  if (t < 256) {
    unsigned run = 0;
#pragma unroll
    for (int w = 0; w < 16; ++w) {
      unsigned c = cnt[w][t];
      cnt[w][t] = run;
      run += c;
    }
    tot[t] = run;
    sc[t] = run;
  }
  __syncthreads();
  for (int off = 1; off < 256; off <<= 1) {
    unsigned v = 0;
    if (t < 256 && t >= off) v = sc[t - off];
    __syncthreads();
    if (t < 256) sc[t] += v;
    __syncthreads();
  }
  if (t < 256) {
    base[t] = t ? sc[t - 1] : 0u;
    unsigned c = tot[t];
    gb[t] = c ? atomicAdd(&bCnt[t], c) : 0u;
  }
  __syncthreads();

#pragma unroll
  for (int j = 0; j < 8; ++j)
    if (bk[j] >= 0) buf[base[bk[j]] + cnt[wave][bk[j]] + po[j]] = pk[j];
  __syncthreads();

  for (int b = wave; b < NB; b += 16) {
    unsigned cb = tot[b];
    if (!cb) continue;
    unsigned lo = base[b], g = gb[b];
    size_t dst = (size_t)b * (unsigned)capA;
    for (unsigned u = lane; u < cb; u += 64)
      if (g + u < (unsigned)capA) pairs[dst + g + u] = buf[lo + u];
  }
}

__global__ __launch_bounds__(256) void k_bscan(const unsigned* __restrict__ bCnt,
                                               unsigned* __restrict__ bBase, int NB) {
  __shared__ unsigned sc[256];
  int t = threadIdx.x;
  unsigned v = (t < NB) ? min(bCnt[t], (unsigned)CAPB) : 0u;
  sc[t] = v;
  __syncthreads();
  for (int off = 1; off < 256; off <<= 1) {
    unsigned u = (t >= off) ? sc[t - off] : 0u;
    __syncthreads();
    sc[t] += u;
    __syncthreads();
  }
  if (t < NB) bBase[t] = t ? sc[t - 1] : 0u;
}

// ---- pass B: per-bucket local CSR; 512 threads = 1 thread per local row ----
__global__ __launch_bounds__(512) void k_binB(
    const unsigned* __restrict__ pairs, const unsigned* __restrict__ bCnt,
    const unsigned* __restrict__ bBase, int* __restrict__ colS,
    unsigned* __restrict__ start, float* __restrict__ dis,
    int N, int capA)
{
  __shared__ unsigned hist[BROWS], cur[BROWS], sc[BROWS];
  __shared__ unsigned cols[CAPB];
  const int t = threadIdx.x;
  const int b = blockIdx.x;
  const unsigned cnt = min(bCnt[b], (unsigned)CAPB);
  const unsigned gbase = bBase[b];
  const size_t src = (size_t)b * (unsigned)capA;

  hist[t] = 0;
  __syncthreads();
  for (unsigned i = t; i < cnt; i += 512)
    atomicAdd(&hist[pairs[src + i] >> 17], 1u);
  __syncthreads();
  const unsigned h = hist[t];
  sc[t] = h;
  __syncthreads();
  for (int off = 1; off < 512; off <<= 1) {
    unsigned v = (t >= off) ? sc[t - off] : 0u;
    __syncthreads();
    sc[t] += v;
    __syncthreads();
  }
  const unsigned e = sc[t] - h;
  cur[t] = e;
  __syncthreads();
  for (unsigned i = t; i < cnt; i += 512) {
    unsigned p = pairs[src + i];
    unsigned pos = atomicAdd(&cur[p >> 17], 1u);
    cols[pos] = p & 0x1FFFFu;
  }
  __syncthreads();
  for (unsigned i = t; i < cnt; i += 512)
    colS[gbase + i] = (int)cols[i];
  const int n = b * BROWS + t;
  if (n < N) {
    start[n] = gbase + e + h;       // segment END offset
    dis[n] = h ? rsqrtf((float)h) : 0.f;
  }
}

// ---------------- fallback-path CSR build -----------------------------------
__global__ __launch_bounds__(256) void k_deg(const int* __restrict__ row,
                                             unsigned* __restrict__ deg, int nE) {
  int i = blockIdx.x * blockDim.x + threadIdx.x;
  int stride = gridDim.x * blockDim.x;
  for (; i < nE; i += stride) atomicAdd(&deg[row[i]], 1u);
}

__global__ __launch_bounds__(256) void k_dis(const unsigned* __restrict__ deg,
                                             float* __restrict__ dis, int n) {
  int i = blockIdx.x * blockDim.x + threadIdx.x;
  if (i < n) {
    unsigned d = deg[i];
    dis[i] = d > 0u ? rsqrtf((float)d) : 0.f;
  }
}

__global__ __launch_bounds__(256) void k_scan1(const unsigned* __restrict__ deg,
                                               unsigned* __restrict__ start,
                                               unsigned* __restrict__ bsum, int n) {
  __shared__ unsigned s[256];
  const int base = blockIdx.x * 2048;
  unsigned v[8], tsum = 0;
#pragma unroll
  for (int j = 0; j < 8; ++j) {
    int idx = base + threadIdx.x * 8 + j;
    v[j] = idx < n ? deg[idx] : 0u;
    tsum += v[j];
  }
  s[threadIdx.x] = tsum;
  __syncthreads();
  for (int off = 1; off < 256; off <<= 1) {
    unsigned t = (threadIdx.x >= off) ? s[threadIdx.x - off] : 0u;
    __syncthreads();
    s[threadIdx.x] += t;
    __syncthreads();
  }
  unsigned run = threadIdx.x ? s[threadIdx.x - 1] : 0u;
  if (threadIdx.x == 255) bsum[blockIdx.x] = s[255];
#pragma unroll
  for (int j = 0; j < 8; ++j) {
    int idx = base + threadIdx.x * 8 + j;
    if (idx < n) start[idx] = run;
    run += v[j];
  }
}

__global__ void k_scan2(unsigned* __restrict__ bsum, int nB) {
  if (threadIdx.x == 0 && blockIdx.x == 0) {
    unsigned run = 0;
    for (int b = 0; b < nB; ++b) { unsigned t = bsum[b]; bsum[b] = run; run += t; }
  }
}

__global__ __launch_bounds__(256) void k_scan3(unsigned* __restrict__ start,
                                               const unsigned* __restrict__ bsum, int n) {
  int i = blockIdx.x * blockDim.x + threadIdx.x;
  if (i < n) start[i] += bsum[i >> 11];
}

__global__ __launch_bounds__(256) void k_build(const int* __restrict__ row,
                                               const int* __restrict__ col,
                                               unsigned* __restrict__ start,
                                               int* __restrict__ colS, int nE) {
  int i = blockIdx.x * blockDim.x + threadIdx.x;
  int stride = gridDim.x * blockDim.x;
  for (; i < nE; i += stride) {
    int r = row[i];
    unsigned p = atomicAdd(&start[r], 1u);
    colS[p] = col[i];
  }
}

// ---------------- edge records + rs (once; layer-invariant) -----------------
__global__ __launch_bounds__(256) void k_wgt(
    const int* __restrict__ colS, const unsigned* __restrict__ startEnd,
    const float* __restrict__ dis, uint2* __restrict__ rec,
    float* __restrict__ rs, int nNodes)
{
  const int t = threadIdx.x;
  const int sub = t & 15;
  const int n = blockIdx.x * 16 + (t >> 4);
  if (n >= nNodes) return;
  const unsigned lo = n ? startEnd[n - 1] : 0u;
  const unsigned hi = startEnd[n];
  float s = 0.f;
  for (unsigned u = lo + sub; u < hi; u += 16) {
    int c = colS[u];
    float w = dis[c];
    rec[u] = make_uint2((unsigned)c, __float_as_uint(w));
    s += w;
  }
  s += __shfl_xor(s, 1); s += __shfl_xor(s, 2);
  s += __shfl_xor(s, 4); s += __shfl_xor(s, 8);
  if (sub == 0) rs[n] = dis[n] * s;
}

// ---------------- f32 -> bf16 cast ------------------------------------------
__global__ __launch_bounds__(256) void k_cast(const float4* __restrict__ x4,
                                              ushort4* __restrict__ out, int n4) {
  int i = blockIdx.x * blockDim.x + threadIdx.x;
  int stride = gridDim.x * blockDim.x;
  for (; i < n4; i += stride) {
    float4 f = x4[i];
    ushort4 v;
    v.x = f2bf(f.x); v.y = f2bf(f.y); v.z = f2bf(f.z); v.w = f2bf(f.w);
    out[i] = v;
  }
}

// ---------------- weight prep: UT[layer][kq][o] -----------------------------
__global__ __launch_bounds__(256) void k_prep(
    const float* __restrict__ W1, const float* __restrict__ b1,
    const float* __restrict__ Wr1, const float* __restrict__ br1,
    const float* __restrict__ W2, const float* __restrict__ b2,
    const float* __restrict__ Wr2, const float* __restrict__ br2,
    float4* __restrict__ UT)
{
  int i = blockIdx.x * 256 + threadIdx.x;
  if (i >= 2 * 33 * 64) return;
  int layer = i / (33 * 64);
  int kq = (i / 64) % 33;
  int o = i % 64;
  const float* W  = layer ? W2  : W1;
  const float* Wr = layer ? Wr2 : Wr1;
  const float* b  = layer ? b2  : b1;
  const float* br = layer ? br2 : br1;
  float4 v;
  if (kq < 16)       v = ((const float4*)W)[o * 16 + kq];
  else if (kq < 32)  v = ((const float4*)Wr)[o * 16 + kq - 16];
  else               v = make_float4(b[o], br[o], 0.f, 0.f);
  UT[i] = v;
}

// ---------------- spmm: aggh[n,:] = bf16(dis[n]*sum w_e*x[c_e,:]) -----------
// 16-lane group owns nodes 2g and 2g+1 (contiguous CSR ranges). Main loop
// interleaves 4 edges of each -> 8 independent gathers in flight per lane.
__global__ __launch_bounds__(256) void k_spmm_rec(
    const u16* __restrict__ xh, u16* __restrict__ aggh,
    const uint2* __restrict__ rec, const unsigned* __restrict__ startEnd,
    const float* __restrict__ dis, int nNodes)
{
  const int t = threadIdx.x;
  const int sub = t & 15;
  const int g = blockIdx.x * 16 + (t >> 4);
  const int nA = 2 * g;
  if (nA >= nNodes) return;
  const int nB = nA + 1;
  const bool hasB = nB < nNodes;
  const unsigned loA = nA ? startEnd[nA - 1] : 0u;
  const unsigned hiA = startEnd[nA];
  const unsigned hiB = hasB ? startEnd[nB] : hiA;   // loB == hiA (contiguous)
  const ushort4* h4 = (const ushort4*)xh;

  float aAx = 0.f, aAy = 0.f, aAz = 0.f, aAw = 0.f;
  float aBx = 0.f, aBy = 0.f, aBz = 0.f, aBw = 0.f;

  unsigned pA = loA, pB = hiA;
  // interleaved main loop: 4 edges of A + 4 edges of B in flight
  while (pA + 4 <= hiA && pB + 4 <= hiB) {
    uint2 rA0 = rec[pA],     rA1 = rec[pA + 1];
    uint2 rA2 = rec[pA + 2], rA3 = rec[pA + 3];
    uint2 rB0 = rec[pB],     rB1 = rec[pB + 1];
    uint2 rB2 = rec[pB + 2], rB3 = rec[pB + 3];
    ushort4 vA0 = h4[(size_t)rA0.x * 16 + sub];
    ushort4 vA1 = h4[(size_t)rA1.x * 16 + sub];
    ushort4 vA2 = h4[(size_t)rA2.x * 16 + sub];
    ushort4 vA3 = h4[(size_t)rA3.x * 16 + sub];
    ushort4 vB0 = h4[(size_t)rB0.x * 16 + sub];
    ushort4 vB1 = h4[(size_t)rB1.x * 16 + sub];
    ushort4 vB2 = h4[(size_t)rB2.x * 16 + sub];
    ushort4 vB3 = h4[(size_t)rB3.x * 16 + sub];
    float wA0 = __uint_as_float(rA0.y), wA1 = __uint_as_float(rA1.y);
    float wA2 = __uint_as_float(rA2.y), wA3 = __uint_as_float(rA3.y);
    float wB0 = __uint_as_float(rB0.y), wB1 = __uint_as_float(rB1.y);
    float wB2 = __uint_as_float(rB2.y), wB3 = __uint_as_float(rB3.y);
    aAx += wA0 * bf2f(vA0.x) + wA1 * bf2f(vA1.x) + wA2 * bf2f(vA2.x) + wA3 * bf2f(vA3.x);
    aAy += wA0 * bf2f(vA0.y) + wA1 * bf2f(vA1.y) + wA2 * bf2f(vA2.y) + wA3 * bf2f(vA3.y);
    aAz += wA0 * bf2f(vA0.z) + wA1 * bf2f(vA1.z) + wA2 * bf2f(vA2.z) + wA3 * bf2f(vA3.z);
    aAw += wA0 * bf2f(vA0.w) + wA1 * bf2f(vA1.w) + wA2 * bf2f(vA2.w) + wA3 * bf2f(vA3.w);
    aBx += wB0 * bf2f(vB0.x) + wB1 * bf2f(vB1.x) + wB2 * bf2f(vB2.x) + wB3 * bf2f(vB3.x);
    aBy += wB0 * bf2f(vB0.y) + wB1 * bf2f(vB1.y) + wB2 * bf2f(vB2.y) + wB3 * bf2f(vB3.y);
    aBz += wB0 * bf2f(vB0.z) + wB1 * bf2f(vB1.z) + wB2 * bf2f(vB2.z) + wB3 * bf2f(vB3.z);
    aBw += wB0 * bf2f(vB0.w) + wB1 * bf2f(vB1.w) + wB2 * bf2f(vB2.w) + wB3 * bf2f(vB3.w);
    pA += 4; pB += 4;
  }
  // drain A (4-deep then scalar)
  for (; pA + 4 <= hiA; pA += 4) {
    uint2 r0 = rec[pA],     r1 = rec[pA + 1];
    uint2 r2 = rec[pA + 2], r3 = rec[pA + 3];
    ushort4 v0 = h4[(size_t)r0.x * 16 + sub];
    ushort4 v1 = h4[(size_t)r1.x * 16 + sub];
    ushort4 v2 = h4[(size_t)r2.x * 16 + sub];
    ushort4 v3 = h4[(size_t)r3.x * 16 + sub];
    float w0 = __uint_as_float(r0.y), w1 = __uint_as_float(r1.y);
    float w2 = __uint_as_float(r2.y), w3 = __uint_as_float(r3.y);
    aAx += w0 * bf2f(v0.x) + w1 * bf2f(v1.x) + w2 * bf2f(v2.x) + w3 * bf2f(v3.x);
    aAy += w0 * bf2f(v0.y) + w1 * bf2f(v1.y) + w2 * bf2f(v2.y) + w3 * bf2f(v3.y);
    aAz += w0 * bf2f(v0.z) + w1 * bf2f(v1.z) + w2 * bf2f(v2.z) + w3 * bf2f(v3.z);
    aAw += w0 * bf2f(v0.w) + w1 * bf2f(v1.w) + w2 * bf2f(v2.w) + w3 * bf2f(v3.w);
  }
  for (; pA < hiA; ++pA) {
    uint2 r = rec[pA];
    ushort4 v = h4[(size_t)r.x * 16 + sub];
    float w = __uint_as_float(r.y);
    aAx += w * bf2f(v.x); aAy += w * bf2f(v.y);
    aAz += w * bf2f(v.z); aAw += w * bf2f(v.w);
  }
  // drain B
  for (; pB + 4 <= hiB; pB += 4) {
    uint2 r0 = rec[pB],     r1 = rec[pB + 1];
    uint2 r2 = rec[pB + 2], r3 = rec[pB + 3];
    ushort4 v0 = h4[(size_t)r0.x * 16 + sub];
    ushort4 v1 = h4[(size_t)r1.x * 16 + sub];
    ushort4 v2 = h4[(size_t)r2.x * 16 + sub];
    ushort4 v3 = h4[(size_t)r3.x * 16 + sub];
    float w0 = __uint_as_float(r0.y), w1 = __uint_as_float(r1.y);
    float w2 = __uint_as_float(r2.y), w3 = __uint_as_float(r3.y);
    aBx += w0 * bf2f(v0.x) + w1 * bf2f(v1.x) + w2 * bf2f(v2.x) + w3 * bf2f(v3.x);
    aBy += w0 * bf2f(v0.y) + w1 * bf2f(v1.y) + w2 * bf2f(v2.y) + w3 * bf2f(v3.y);
    aBz += w0 * bf2f(v0.z) + w1 * bf2f(v1.z) + w2 * bf2f(v2.z) + w3 * bf2f(v3.z);
    aBw += w0 * bf2f(v0.w) + w1 * bf2f(v1.w) + w2 * bf2f(v2.w) + w3 * bf2f(v3.w);
  }
  for (; pB < hiB; ++pB) {
    uint2 r = rec[pB];
    ushort4 v = h4[(size_t)r.x * 16 + sub];
    float w = __uint_as_float(r.y);
    aBx += w * bf2f(v.x); aBy += w * bf2f(v.y);
    aBz += w * bf2f(v.z); aBw += w * bf2f(v.w);
  }

  const float dA = dis[nA];
  ushort4 oA;
  oA.x = f2bf(dA * aAx); oA.y = f2bf(dA * aAy);
  oA.z = f2bf(dA * aAz); oA.w = f2bf(dA * aAw);
  ((ushort4*)aggh)[(size_t)nA * 16 + sub] = oA;
  if (hasB) {
    const float dB = dis[nB];
    ushort4 oB;
    oB.x = f2bf(dB * aBx); oB.y = f2bf(dB * aBy);
    oB.z = f2bf(dB * aBz); oB.w = f2bf(dB * aBw);
    ((ushort4*)aggh)[(size_t)nB * 16 + sub] = oB;
  }
}

// ---------------- gemv: x_out = relu(agg@W^T + rs*b + root@Wr^T + br) -------
__global__ __launch_bounds__(256) void k_gemv(
    const u16* __restrict__ aggh, const float* __restrict__ rs,
    const u16* __restrict__ rooth, const float4* __restrict__ UT,
    u16* __restrict__ xo, int nNodes)
{
  __shared__ u16 xsh[64][136];
  const int t = threadIdx.x;
  const int lane = t & 63;
  const int og = __builtin_amdgcn_readfirstlane(t >> 6);
  const int n0 = blockIdx.x * 64;

  {
    const int r = t >> 2, q = t & 3;
    int gn = n0 + r; if (gn > nNodes - 1) gn = nNodes - 1;
    const uint4* a = (const uint4*)(aggh + (size_t)gn * 64);
    const uint4* x = (const uint4*)(rooth + (size_t)gn * 64);
    *(uint4*)&xsh[r][q * 16]           = a[q * 2];
    *(uint4*)&xsh[r][q * 16 + 8]       = a[q * 2 + 1];
    *(uint4*)&xsh[r][64 + q * 16]      = x[q * 2];
    *(uint4*)&xsh[r][64 + q * 16 + 8]  = x[q * 2 + 1];
  }
  __syncthreads();

  float acc[16];
#pragma unroll
  for (int j = 0; j < 16; ++j) acc[j] = 0.f;

#pragma unroll 4
  for (int k = 0; k < 32; ++k) {
    ushort4 v = *(const ushort4*)&xsh[lane][k * 4];
    float xa = bf2f(v.x), xb = bf2f(v.y), xc = bf2f(v.z), xd = bf2f(v.w);
    const float4* w = UT + k * 64 + og * 16;
#pragma unroll
    for (int j = 0; j < 16; ++j) {
      float4 W = w[j];
      acc[j] = fmaf(xa, W.x, fmaf(xb, W.y, fmaf(xc, W.z, fmaf(xd, W.w, acc[j]))));
    }
  }

  const int n = n0 + lane;
  const float rsv = (n < nNodes) ? rs[n] : 0.f;
  {
    const float4* w = UT + 32 * 64 + og * 16;
#pragma unroll
    for (int j = 0; j < 16; ++j) {
      float4 W = w[j];
      acc[j] = fmaf(rsv, W.x, acc[j]) + W.y;
    }
  }

  if (n < nNodes) {
    uint4 u0, u1;
    u0.x = (u32)f2bf(fmaxf(acc[0], 0.f))  | ((u32)f2bf(fmaxf(acc[1], 0.f)) << 16);
    u0.y = (u32)f2bf(fmaxf(acc[2], 0.f))  | ((u32)f2bf(fmaxf(acc[3], 0.f)) << 16);
    u0.z = (u32)f2bf(fmaxf(acc[4], 0.f))  | ((u32)f2bf(fmaxf(acc[5], 0.f)) << 16);
    u0.w = (u32)f2bf(fmaxf(acc[6], 0.f))  | ((u32)f2bf(fmaxf(acc[7], 0.f)) << 16);
    u1.x = (u32)f2bf(fmaxf(acc[8], 0.f))  | ((u32)f2bf(fmaxf(acc[9], 0.f)) << 16);
    u1.y = (u32)f2bf(fmaxf(acc[10], 0.f)) | ((u32)f2bf(fmaxf(acc[11], 0.f)) << 16);
    u1.z = (u32)f2bf(fmaxf(acc[12], 0.f)) | ((u32)f2bf(fmaxf(acc[13], 0.f)) << 16);
    u1.w = (u32)f2bf(fmaxf(acc[14], 0.f)) | ((u32)f2bf(fmaxf(acc[15], 0.f)) << 16);
    uint4* dst = (uint4*)(xo + (size_t)n * 64 + og * 16);
    dst[0] = u0;
    dst[1] = u1;
  }
}

// ---------------- head: log_softmax(concat(x1,x2)@Wl^T + bl) ----------------
__global__ __launch_bounds__(256) void k_final(
    const u16* __restrict__ x1h, const u16* __restrict__ x2h,
    const float* __restrict__ Wl, const float* __restrict__ bl,
    float* __restrict__ out, int nNodes)
{
  __shared__ float4 xs[64][33];
  __shared__ float redM[64][4];
  __shared__ float redS[64][4];
  const int t = threadIdx.x;
  const int lane = t & 63;
  const int og = __builtin_amdgcn_readfirstlane(t >> 6);
  const int nodeBase = blockIdx.x * 64;

  {
    const int sn = t >> 2, q = t & 3;
    int gn = nodeBase + sn;
    if (gn > nNodes - 1) gn = nNodes - 1;
    const ushort4* a = (q < 2) ? (const ushort4*)(x1h + (size_t)gn * 64)
                               : (const ushort4*)(x2h + (size_t)gn * 64);
    const int qq = q & 1;
#pragma unroll
    for (int j = 0; j < 8; ++j) {
      ushort4 v = a[qq * 8 + j];
      xs[sn][q * 8 + j] = make_float4(bf2f(v.x), bf2f(v.y), bf2f(v.z), bf2f(v.w));
    }
  }
  __syncthreads();

  const float4* W4 = (const float4*)Wl;
  float acc[10];
#pragma unroll
  for (int j = 0; j < 10; ++j) acc[j] = bl[og * 10 + j];
  for (int k = 0; k < 32; ++k) {
    float4 x = xs[lane][k];
#pragma unroll
    for (int j = 0; j < 10; ++j) {
      float4 w = W4[(og * 10 + j) * 32 + k];
      acc[j] += w.x * x.x + w.y * x.y + w.z * x.z + w.w * x.w;
    }
  }

  float m10 = acc[0];
#pragma unroll
  for (int j = 1; j < 10; ++j) m10 = fmaxf(m10, acc[j]);
  redM[lane][og] = m10;
  __syncthreads();
  float M = fmaxf(fmaxf(redM[lane][0], redM[lane][1]),
                  fmaxf(redM[lane][2], redM[lane][3]));
  float s10 = 0.f;
#pragma unroll
  for (int j = 0; j < 10; ++j) s10 += __expf(acc[j] - M);
  redS[lane][og] = s10;
  __syncthreads();
  const float S = redS[lane][0] + redS[lane][1] + redS[lane][2] + redS[lane][3];
  const float lse = M + __logf(S);

  const int n = nodeBase + lane;
  if (n < nNodes) {
    float2* o2 = (float2*)(out + (size_t)n * 40 + og * 10);
#pragma unroll
    for (int q = 0; q < 5; ++q)
      o2[q] = make_float2(acc[2 * q] - lse, acc[2 * q + 1] - lse);
  }
}

extern "C" void kernel_launch(void* const* d_in, const int* in_sizes, int n_in,
                              void* d_out, int out_size, void* d_ws, size_t ws_size,
                              hipStream_t stream) {
  const float* x0  = (const float*)d_in[0];
  const int*   ei  = (const int*)d_in[1];
  const float* W1  = (const float*)d_in[2];
  const float* b1  = (const float*)d_in[3];
  const float* Wr1 = (const float*)d_in[4];
  const float* br1 = (const float*)d_in[5];
  const float* W2  = (const float*)d_in[6];
  const float* b2  = (const float*)d_in[7];
  const float* Wr2 = (const float*)d_in[8];
  const float* br2 = (const float*)d_in[9];
  const float* Wl  = (const float*)d_in[10];
  const float* bl  = (const float*)d_in[11];
  float* out = (float*)d_out;

  const int N = in_sizes[0] / 64;
  const int E = in_sizes[1] / 2;
  const int* row = ei;
  const int* col = ei + E;

  const int NB = (N + BROWS - 1) / BROWS;
  const int capA = 16384;
  const int avg = E / (NB > 0 ? NB : 1);
  const bool binOK = (N <= 131072) && (NB <= 256) &&
                     (avg + 12 * (int)sqrtf((float)avg + 1.f) + 256 <= CAPB);

  size_t P = (size_t)NB * capA;
  if (P < (size_t)32 * N) P = (size_t)32 * N;

  const size_t UT_W = 2 * 33 * 64 * 4;  // words
  // bin: bCnt256|bBase256|P|colS E|rec 2E|start N|dis N|rs N|UT|aggh 32N|x1h 32N
  const size_t needBin = 4 * (512 + P + (size_t)3 * E + (size_t)3 * N + UT_W +
                              (size_t)32 * N + (size_t)32 * N);
  // csr: deg N|start N|dis N|rs N|bsum64|colS E|rec 2E|UT|aggh 32N|x1h 32N|xsh 32N
  const size_t needCSR = 4 * ((size_t)4 * N + 64 + (size_t)3 * E + UT_W +
                              (size_t)32 * N + (size_t)32 * N + (size_t)32 * N);

  unsigned *start = nullptr; float *dis = nullptr, *rsv = nullptr;
  int* colS = nullptr; uint2* rec = nullptr; float4* UT = nullptr;
  u16 *aggh = nullptr, *x0h = nullptr, *x1h = nullptr, *x2h = nullptr;
  bool ok = false;

  if (binOK && ws_size >= needBin) {
    unsigned* bCnt  = (unsigned*)d_ws;
    unsigned* bBase = bCnt + 256;
    unsigned* pairs = bBase + 256;
    colS  = (int*)(pairs + P);
    rec   = (uint2*)(colS + E);
    start = (unsigned*)(rec + E);
    dis   = (float*)(start + N);
    rsv   = dis + N;
    UT    = (float4*)(rsv + N);
    aggh  = (u16*)(UT + 2 * 33 * 64);
    x1h   = aggh + (size_t)64 * N;
    x0h   = (u16*)pairs;
    x2h   = (u16*)pairs;

    hipMemsetAsync(bCnt, 0, 256 * 4, stream);
    k_binA<<<(E + BIN_CHUNK - 1) / BIN_CHUNK, 1024, 0, stream>>>(row, col, bCnt, pairs, E, NB, capA);
    k_bscan<<<1, 256, 0, stream>>>(bCnt, bBase, NB);
    k_binB<<<NB, 512, 0, stream>>>(pairs, bCnt, bBase, colS, start, dis, N, capA);
    ok = true;
  } else if (ws_size >= needCSR) {
    unsigned* deg = (unsigned*)d_ws;
    start = deg + N;                 // becomes segment-END after k_build
    dis   = (float*)(start + N);
    rsv   = dis + N;
    unsigned* bsum = (unsigned*)(rsv + N);
    colS  = (int*)(bsum + 64);
    rec   = (uint2*)(colS + E);
    UT    = (float4*)(rec + E);
    aggh  = (u16*)(UT + 2 * 33 * 64);
    x1h   = aggh + (size_t)64 * N;
    u16* xsh = x1h + (size_t)64 * N;
    x0h = xsh; x2h = xsh;

    const int nB = (N + 2047) / 2048;
    hipMemsetAsync(deg, 0, (size_t)N * 4, stream);
    k_deg<<<1024, 256, 0, stream>>>(row, deg, E);
    k_dis<<<(N + 255) / 256, 256, 0, stream>>>(deg, dis, N);
    k_scan1<<<nB, 256, 0, stream>>>(deg, start, bsum, N);
    k_scan2<<<1, 64, 0, stream>>>(bsum, nB);
    k_scan3<<<(N + 255) / 256, 256, 0, stream>>>(start, bsum, N);
    k_build<<<1024, 256, 0, stream>>>(row, col, start, colS, E);
    ok = true;
  }

  if (!ok) return;

  k_wgt<<<(N + 15) / 16, 256, 0, stream>>>(colS, start, dis, rec, rsv, N);
  k_cast<<<1024, 256, 0, stream>>>((const float4*)x0, (ushort4*)x0h, N * 16);
  k_prep<<<17, 256, 0, stream>>>(W1, b1, Wr1, br1, W2, b2, Wr2, br2, UT);

  const int nPairs = (N + 1) / 2;
  const int spmmBlocks = (nPairs + 15) / 16;

  // layer 1
  k_spmm_rec<<<spmmBlocks, 256, 0, stream>>>(x0h, aggh, rec, start, dis, N);
  k_gemv<<<(N + 63) / 64, 256, 0, stream>>>(aggh, rsv, x0h, UT, x1h, N);

  // layer 2
  k_spmm_rec<<<spmmBlocks, 256, 0, stream>>>(x1h, aggh, rec, start, dis, N);
  k_gemv<<<(N + 63) / 64, 256, 0, stream>>>(aggh, rsv, x1h, UT + 33 * 64, x2h, N);

  // head
  k_final<<<(N + 63) / 64, 256, 0, stream>>>(x1h, x2h, Wl, bl, out, N);
}

// Round 16
// 225.053 us; speedup vs baseline: 1.1427x; 1.0659x over previous
//
#include <hip/hip_runtime.h>
#include <math.h>

// ---------------------------------------------------------------------------
// SAINT-style 2-layer graph conv + linear head + log_softmax
// N=100000 nodes, E=1600000 edges, C=64, HID=64, OUT=40
// Round 15: final revert to the round-9 pipeline (best measured: 225us).
// spmm = 16-lane group/node, 4-deep gather unroll; rec[] built once by k_wgt.
// spmm floor argument: per-XCD compulsory L2 refill of the 12.8MB bf16 table
// (8 XCDs -> <=102MB/layer; measured 83MB) at ~2.1TB/s L2-miss rate = ~40us.
// ---------------------------------------------------------------------------

typedef unsigned short u16;
typedef unsigned int   u32;

#define BROWS 512
#define BIN_CHUNK 8192
#define CAPB 12288         // per-bucket capacity clamp

__device__ __forceinline__ u16 f2bf(float f) {
  u32 u = __float_as_uint(f);
  u32 r = u + 0x7fffu + ((u >> 16) & 1u);
  return (u16)(r >> 16);
}
__device__ __forceinline__ float bf2f(u16 h) {
  return __uint_as_float(((u32)h) << 16);
}

// ---- pass A: bin edges into NB bucket regions, packed (lrow<<17)|col -------
__global__ __launch_bounds__(1024) void k_binA(
    const int* __restrict__ row, const int* __restrict__ col,
    unsigned* __restrict__ bCnt, unsigned* __restrict__ pairs,
    int nE, int NB, int capA)
{
  __shared__ unsigned buf[BIN_CHUNK];
  __shared__ unsigned cnt[16][256];
  __shared__ unsigned base[256], gb[256], tot[256], sc[256];
  const int t = threadIdx.x;
  const int wave = t >> 6, lane = t & 63;
  const int tb = blockIdx.x * BIN_CHUNK;

  for (int i = t; i < 16 * 256; i += 1024) ((unsigned*)cnt)[i] = 0;
  __syncthreads();

  unsigned pk[8];
  unsigned short po[8];
  short bk[8];
#pragma unroll
  for (int j = 0; j < 8; ++j) {
    int i = tb + j * 1024 + t;
    if (i < nE) {
      int r = row[i], c = col[i];
      int b = r >> 9;
      pk[j] = ((unsigned)(r & (BROWS - 1)) << 17) | (unsigned)c;
      bk[j] = (short)b;
      po[j] = (unsigned short)atomicAdd(&cnt[wave][b], 1u);
    } else bk[j] = -1;
  }
  __syncthreads();

  if (t < 256) {
    unsigned run = 0;
#pragma unroll
    for (int w = 0; w < 16; ++w) {
      unsigned c = cnt[w][t];
      cnt[w][t] = run;
      run += c;
    }
    tot[t] = run;
    sc[t] = run;
  }
  __syncthreads();
  for (int off = 1; off < 256; off <<= 1) {
    unsigned v = 0;
    if (t < 256 && t >= off) v = sc[t - off];
    __syncthreads();
    if (t < 256) sc[t] += v;
    __syncthreads();
  }
  if (t < 256) {
    base[t] = t ? sc[t - 1] : 0u;
    unsigned c = tot[t];
    gb[t] = c ? atomicAdd(&bCnt[t], c) : 0u;
  }
  __syncthreads();

#pragma unroll
  for (int j = 0; j < 8; ++j)
    if (bk[j] >= 0) buf[base[bk[j]] + cnt[wave][bk[j]] + po[j]] = pk[j];
  __syncthreads();

  for (int b = wave; b < NB; b += 16) {
    unsigned cb = tot[b];
    if (!cb) continue;
    unsigned lo = base[b], g = gb[b];
    size_t dst = (size_t)b * (unsigned)capA;
    for (unsigned u = lane; u < cb; u += 64)
      if (g + u < (unsigned)capA) pairs[dst + g + u] = buf[lo + u];
  }
}

__global__ __launch_bounds__(256) void k_bscan(const unsigned* __restrict__ bCnt,
                                               unsigned* __restrict__ bBase, int NB) {
  __shared__ unsigned sc[256];
  int t = threadIdx.x;
  unsigned v = (t < NB) ? min(bCnt[t], (unsigned)CAPB) : 0u;
  sc[t] = v;
  __syncthreads();
  for (int off = 1; off < 256; off <<= 1) {
    unsigned u = (t >= off) ? sc[t - off] : 0u;
    __syncthreads();
    sc[t] += u;
    __syncthreads();
  }
  if (t < NB) bBase[t] = t ? sc[t - 1] : 0u;
}

// ---- pass B: per-bucket local CSR; 512 threads = 1 thread per local row ----
__global__ __launch_bounds__(512) void k_binB(
    const unsigned* __restrict__ pairs, const unsigned* __restrict__ bCnt,
    const unsigned* __restrict__ bBase, int* __restrict__ colS,
    unsigned* __restrict__ start, float* __restrict__ dis,
    int N, int capA)
{
  __shared__ unsigned hist[BROWS], cur[BROWS], sc[BROWS];
  __shared__ unsigned cols[CAPB];
  const int t = threadIdx.x;
  const int b = blockIdx.x;
  const unsigned cnt = min(bCnt[b], (unsigned)CAPB);
  const unsigned gbase = bBase[b];
  const size_t src = (size_t)b * (unsigned)capA;

  hist[t] = 0;
  __syncthreads();
  for (unsigned i = t; i < cnt; i += 512)
    atomicAdd(&hist[pairs[src + i] >> 17], 1u);
  __syncthreads();
  const unsigned h = hist[t];
  sc[t] = h;
  __syncthreads();
  for (int off = 1; off < 512; off <<= 1) {
    unsigned v = (t >= off) ? sc[t - off] : 0u;
    __syncthreads();
    sc[t] += v;
    __syncthreads();
  }
  const unsigned e = sc[t] - h;
  cur[t] = e;
  __syncthreads();
  for (unsigned i = t; i < cnt; i += 512) {
    unsigned p = pairs[src + i];
    unsigned pos = atomicAdd(&cur[p >> 17], 1u);
    cols[pos] = p & 0x1FFFFu;
  }
  __syncthreads();
  for (unsigned i = t; i < cnt; i += 512)
    colS[gbase + i] = (int)cols[i];
  const int n = b * BROWS + t;
  if (n < N) {
    start[n] = gbase + e + h;       // segment END offset
    dis[n] = h ? rsqrtf((float)h) : 0.f;
  }
}

// ---------------- fallback-path CSR build -----------------------------------
__global__ __launch_bounds__(256) void k_deg(const int* __restrict__ row,
                                             unsigned* __restrict__ deg, int nE) {
  int i = blockIdx.x * blockDim.x + threadIdx.x;
  int stride = gridDim.x * blockDim.x;
  for (; i < nE; i += stride) atomicAdd(&deg[row[i]], 1u);
}

__global__ __launch_bounds__(256) void k_dis(const unsigned* __restrict__ deg,
                                             float* __restrict__ dis, int n) {
  int i = blockIdx.x * blockDim.x + threadIdx.x;
  if (i < n) {
    unsigned d = deg[i];
    dis[i] = d > 0u ? rsqrtf((float)d) : 0.f;
  }
}

__global__ __launch_bounds__(256) void k_scan1(const unsigned* __restrict__ deg,
                                               unsigned* __restrict__ start,
                                               unsigned* __restrict__ bsum, int n) {
  __shared__ unsigned s[256];
  const int base = blockIdx.x * 2048;
  unsigned v[8], tsum = 0;
#pragma unroll
  for (int j = 0; j < 8; ++j) {
    int idx = base + threadIdx.x * 8 + j;
    v[j] = idx < n ? deg[idx] : 0u;
    tsum += v[j];
  }
  s[threadIdx.x] = tsum;
  __syncthreads();
  for (int off = 1; off < 256; off <<= 1) {
    unsigned t = (threadIdx.x >= off) ? s[threadIdx.x - off] : 0u;
    __syncthreads();
    s[threadIdx.x] += t;
    __syncthreads();
  }
  unsigned run = threadIdx.x ? s[threadIdx.x - 1] : 0u;
  if (threadIdx.x == 255) bsum[blockIdx.x] = s[255];
#pragma unroll
  for (int j = 0; j < 8; ++j) {
    int idx = base + threadIdx.x * 8 + j;
    if (idx < n) start[idx] = run;
    run += v[j];
  }
}

__global__ void k_scan2(unsigned* __restrict__ bsum, int nB) {
  if (threadIdx.x == 0 && blockIdx.x == 0) {
    unsigned run = 0;
    for (int b = 0; b < nB; ++b) { unsigned t = bsum[b]; bsum[b] = run; run += t; }
  }
}

__global__ __launch_bounds__(256) void k_scan3(unsigned* __restrict__ start,
                                               const unsigned* __restrict__ bsum, int n) {
  int i = blockIdx.x * blockDim.x + threadIdx.x;
  if (i < n) start[i] += bsum[i >> 11];
}

__global__ __launch_bounds__(256) void k_build(const int* __restrict__ row,
                                               const int* __restrict__ col,
                                               unsigned* __restrict__ start,
                                               int* __restrict__ colS, int nE) {
  int i = blockIdx.x * blockDim.x + threadIdx.x;
  int stride = gridDim.x * blockDim.x;
  for (; i < nE; i += stride) {
    int r = row[i];
    unsigned p = atomicAdd(&start[r], 1u);
    colS[p] = col[i];
  }
}

// ---------------- edge records + rs (once; layer-invariant) -----------------
__global__ __launch_bounds__(256) void k_wgt(
    const int* __restrict__ colS, const unsigned* __restrict__ startEnd,
    const float* __restrict__ dis, uint2* __restrict__ rec,
    float* __restrict__ rs, int nNodes)
{
  const int t = threadIdx.x;
  const int sub = t & 15;
  const int n = blockIdx.x * 16 + (t >> 4);
  if (n >= nNodes) return;
  const unsigned lo = n ? startEnd[n - 1] : 0u;
  const unsigned hi = startEnd[n];
  float s = 0.f;
  for (unsigned u = lo + sub; u < hi; u += 16) {
    int c = colS[u];
    float w = dis[c];
    rec[u] = make_uint2((unsigned)c, __float_as_uint(w));
    s += w;
  }
  s += __shfl_xor(s, 1); s += __shfl_xor(s, 2);
  s += __shfl_xor(s, 4); s += __shfl_xor(s, 8);
  if (sub == 0) rs[n] = dis[n] * s;
}

// ---------------- f32 -> bf16 cast ------------------------------------------
__global__ __launch_bounds__(256) void k_cast(const float4* __restrict__ x4,
                                              ushort4* __restrict__ out, int n4) {
  int i = blockIdx.x * blockDim.x + threadIdx.x;
  int stride = gridDim.x * blockDim.x;
  for (; i < n4; i += stride) {
    float4 f = x4[i];
    ushort4 v;
    v.x = f2bf(f.x); v.y = f2bf(f.y); v.z = f2bf(f.z); v.w = f2bf(f.w);
    out[i] = v;
  }
}

// ---------------- weight prep: UT[layer][kq][o] -----------------------------
__global__ __launch_bounds__(256) void k_prep(
    const float* __restrict__ W1, const float* __restrict__ b1,
    const float* __restrict__ Wr1, const float* __restrict__ br1,
    const float* __restrict__ W2, const float* __restrict__ b2,
    const float* __restrict__ Wr2, const float* __restrict__ br2,
    float4* __restrict__ UT)
{
  int i = blockIdx.x * 256 + threadIdx.x;
  if (i >= 2 * 33 * 64) return;
  int layer = i / (33 * 64);
  int kq = (i / 64) % 33;
  int o = i % 64;
  const float* W  = layer ? W2  : W1;
  const float* Wr = layer ? Wr2 : Wr1;
  const float* b  = layer ? b2  : b1;
  const float* br = layer ? br2 : br1;
  float4 v;
  if (kq < 16)       v = ((const float4*)W)[o * 16 + kq];
  else if (kq < 32)  v = ((const float4*)Wr)[o * 16 + kq - 16];
  else               v = make_float4(b[o], br[o], 0.f, 0.f);
  UT[i] = v;
}

// ---------------- spmm: aggh[n,:] = bf16(dis[n]*sum w_e*x[c_e,:]) -----------
// 16-lane group per node (4 nodes/wave). rec loads are same-address within a
// group (TA broadcast); x-row gathers ushort4 x 16 lanes = 128B. No cross-lane
// ops. 4-edge manual unroll. (Best measured variant: 40us/dispatch.)
__global__ __launch_bounds__(256) void k_spmm_rec(
    const u16* __restrict__ xh, u16* __restrict__ aggh,
    const uint2* __restrict__ rec, const unsigned* __restrict__ startEnd,
    const float* __restrict__ dis, int nNodes)
{
  const int t = threadIdx.x;
  const int sub = t & 15;
  const int n = blockIdx.x * 16 + (t >> 4);
  if (n >= nNodes) return;
  const unsigned lo = n ? startEnd[n - 1] : 0u;
  const unsigned hi = startEnd[n];
  const ushort4* h4 = (const ushort4*)xh;

  float ax = 0.f, ay = 0.f, az = 0.f, aw = 0.f;
  unsigned p = lo;
  for (; p + 4 <= hi; p += 4) {
    uint2 r0 = rec[p],     r1 = rec[p + 1];
    uint2 r2 = rec[p + 2], r3 = rec[p + 3];
    ushort4 v0 = h4[(size_t)r0.x * 16 + sub];
    ushort4 v1 = h4[(size_t)r1.x * 16 + sub];
    ushort4 v2 = h4[(size_t)r2.x * 16 + sub];
    ushort4 v3 = h4[(size_t)r3.x * 16 + sub];
    float w0 = __uint_as_float(r0.y), w1 = __uint_as_float(r1.y);
    float w2 = __uint_as_float(r2.y), w3 = __uint_as_float(r3.y);
    ax += w0 * bf2f(v0.x) + w1 * bf2f(v1.x) + w2 * bf2f(v2.x) + w3 * bf2f(v3.x);
    ay += w0 * bf2f(v0.y) + w1 * bf2f(v1.y) + w2 * bf2f(v2.y) + w3 * bf2f(v3.y);
    az += w0 * bf2f(v0.z) + w1 * bf2f(v1.z) + w2 * bf2f(v2.z) + w3 * bf2f(v3.z);
    aw += w0 * bf2f(v0.w) + w1 * bf2f(v1.w) + w2 * bf2f(v2.w) + w3 * bf2f(v3.w);
  }
  for (; p < hi; ++p) {
    uint2 r = rec[p];
    ushort4 v = h4[(size_t)r.x * 16 + sub];
    float w = __uint_as_float(r.y);
    ax += w * bf2f(v.x); ay += w * bf2f(v.y);
    az += w * bf2f(v.z); aw += w * bf2f(v.w);
  }
  const float dn = dis[n];
  ushort4 o;
  o.x = f2bf(dn * ax); o.y = f2bf(dn * ay);
  o.z = f2bf(dn * az); o.w = f2bf(dn * aw);
  ((ushort4*)aggh)[(size_t)n * 16 + sub] = o;
}

// ---------------- gemv: x_out = relu(agg@W^T + rs*b + root@Wr^T + br) -------
__global__ __launch_bounds__(256) void k_gemv(
    const u16* __restrict__ aggh, const float* __restrict__ rs,
    const u16* __restrict__ rooth, const float4* __restrict__ UT,
    u16* __restrict__ xo, int nNodes)
{
  __shared__ u16 xsh[64][136];
  const int t = threadIdx.x;
  const int lane = t & 63;
  const int og = __builtin_amdgcn_readfirstlane(t >> 6);
  const int n0 = blockIdx.x * 64;

  {
    const int r = t >> 2, q = t & 3;
    int gn = n0 + r; if (gn > nNodes - 1) gn = nNodes - 1;
    const uint4* a = (const uint4*)(aggh + (size_t)gn * 64);
    const uint4* x = (const uint4*)(rooth + (size_t)gn * 64);
    *(uint4*)&xsh[r][q * 16]           = a[q * 2];
    *(uint4*)&xsh[r][q * 16 + 8]       = a[q * 2 + 1];
    *(uint4*)&xsh[r][64 + q * 16]      = x[q * 2];
    *(uint4*)&xsh[r][64 + q * 16 + 8]  = x[q * 2 + 1];
  }
  __syncthreads();

  float acc[16];
#pragma unroll
  for (int j = 0; j < 16; ++j) acc[j] = 0.f;

#pragma unroll 4
  for (int k = 0; k < 32; ++k) {
    ushort4 v = *(const ushort4*)&xsh[lane][k * 4];
    float xa = bf2f(v.x), xb = bf2f(v.y), xc = bf2f(v.z), xd = bf2f(v.w);
    const float4* w = UT + k * 64 + og * 16;
#pragma unroll
    for (int j = 0; j < 16; ++j) {
      float4 W = w[j];
      acc[j] = fmaf(xa, W.x, fmaf(xb, W.y, fmaf(xc, W.z, fmaf(xd, W.w, acc[j]))));
    }
  }

  const int n = n0 + lane;
  const float rsv = (n < nNodes) ? rs[n] : 0.f;
  {
    const float4* w = UT + 32 * 64 + og * 16;
#pragma unroll
    for (int j = 0; j < 16; ++j) {
      float4 W = w[j];
      acc[j] = fmaf(rsv, W.x, acc[j]) + W.y;
    }
  }

  if (n < nNodes) {
    uint4 u0, u1;
    u0.x = (u32)f2bf(fmaxf(acc[0], 0.f))  | ((u32)f2bf(fmaxf(acc[1], 0.f)) << 16);
    u0.y = (u32)f2bf(fmaxf(acc[2], 0.f))  | ((u32)f2bf(fmaxf(acc[3], 0.f)) << 16);
    u0.z = (u32)f2bf(fmaxf(acc[4], 0.f))  | ((u32)f2bf(fmaxf(acc[5], 0.f)) << 16);
    u0.w = (u32)f2bf(fmaxf(acc[6], 0.f))  | ((u32)f2bf(fmaxf(acc[7], 0.f)) << 16);
    u1.x = (u32)f2bf(fmaxf(acc[8], 0.f))  | ((u32)f2bf(fmaxf(acc[9], 0.f)) << 16);
    u1.y = (u32)f2bf(fmaxf(acc[10], 0.f)) | ((u32)f2bf(fmaxf(acc[11], 0.f)) << 16);
    u1.z = (u32)f2bf(fmaxf(acc[12], 0.f)) | ((u32)f2bf(fmaxf(acc[13], 0.f)) << 16);
    u1.w = (u32)f2bf(fmaxf(acc[14], 0.f)) | ((u32)f2bf(fmaxf(acc[15], 0.f)) << 16);
    uint4* dst = (uint4*)(xo + (size_t)n * 64 + og * 16);
    dst[0] = u0;
    dst[1] = u1;
  }
}

// ---------------- head: log_softmax(concat(x1,x2)@Wl^T + bl) ----------------
__global__ __launch_bounds__(256) void k_final(
    const u16* __restrict__ x1h, const u16* __restrict__ x2h,
    const float* __restrict__ Wl, const float* __restrict__ bl,
    float* __restrict__ out, int nNodes)
{
  __shared__ float4 xs[64][33];
  __shared__ float redM[64][4];
  __shared__ float redS[64][4];
  const int t = threadIdx.x;
  const int lane = t & 63;
  const int og = __builtin_amdgcn_readfirstlane(t >> 6);
  const int nodeBase = blockIdx.x * 64;

  {
    const int sn = t >> 2, q = t & 3;
    int gn = nodeBase + sn;
    if (gn > nNodes - 1) gn = nNodes - 1;
    const ushort4* a = (q < 2) ? (const ushort4*)(x1h + (size_t)gn * 64)
                               : (const ushort4*)(x2h + (size_t)gn * 64);
    const int qq = q & 1;
#pragma unroll
    for (int j = 0; j < 8; ++j) {
      ushort4 v = a[qq * 8 + j];
      xs[sn][q * 8 + j] = make_float4(bf2f(v.x), bf2f(v.y), bf2f(v.z), bf2f(v.w));
    }
  }
  __syncthreads();

  const float4* W4 = (const float4*)Wl;
  float acc[10];
#pragma unroll
  for (int j = 0; j < 10; ++j) acc[j] = bl[og * 10 + j];
  for (int k = 0; k < 32; ++k) {
    float4 x = xs[lane][k];
#pragma unroll
    for (int j = 0; j < 10; ++j) {
      float4 w = W4[(og * 10 + j) * 32 + k];
      acc[j] += w.x * x.x + w.y * x.y + w.z * x.z + w.w * x.w;
    }
  }

  float m10 = acc[0];
#pragma unroll
  for (int j = 1; j < 10; ++j) m10 = fmaxf(m10, acc[j]);
  redM[lane][og] = m10;
  __syncthreads();
  float M = fmaxf(fmaxf(redM[lane][0], redM[lane][1]),
                  fmaxf(redM[lane][2], redM[lane][3]));
  float s10 = 0.f;
#pragma unroll
  for (int j = 0; j < 10; ++j) s10 += __expf(acc[j] - M);
  redS[lane][og] = s10;
  __syncthreads();
  const float S = redS[lane][0] + redS[lane][1] + redS[lane][2] + redS[lane][3];
  const float lse = M + __logf(S);

  const int n = nodeBase + lane;
  if (n < nNodes) {
    float2* o2 = (float2*)(out + (size_t)n * 40 + og * 10);
#pragma unroll
    for (int q = 0; q < 5; ++q)
      o2[q] = make_float2(acc[2 * q] - lse, acc[2 * q + 1] - lse);
  }
}

extern "C" void kernel_launch(void* const* d_in, const int* in_sizes, int n_in,
                              void* d_out, int out_size, void* d_ws, size_t ws_size,
                              hipStream_t stream) {
  const float* x0  = (const float*)d_in[0];
  const int*   ei  = (const int*)d_in[1];
  const float* W1  = (const float*)d_in[2];
  const float* b1  = (const float*)d_in[3];
  const float* Wr1 = (const float*)d_in[4];
  const float* br1 = (const float*)d_in[5];
  const float* W2  = (const float*)d_in[6];
  const float* b2  = (const float*)d_in[7];
  const float* Wr2 = (const float*)d_in[8];
  const float* br2 = (const float*)d_in[9];
  const float* Wl  = (const float*)d_in[10];
  const float* bl  = (const float*)d_in[11];
  float* out = (float*)d_out;

  const int N = in_sizes[0] / 64;
  const int E = in_sizes[1] / 2;
  const int* row = ei;
  const int* col = ei + E;

  const int NB = (N + BROWS - 1) / BROWS;
  const int capA = 16384;
  const int avg = E / (NB > 0 ? NB : 1);
  const bool binOK = (N <= 131072) && (NB <= 256) &&
                     (avg + 12 * (int)sqrtf((float)avg + 1.f) + 256 <= CAPB);

  size_t P = (size_t)NB * capA;
  if (P < (size_t)32 * N) P = (size_t)32 * N;

  const size_t UT_W = 2 * 33 * 64 * 4;  // words
  // bin: bCnt256|bBase256|P|colS E|rec 2E|start N|dis N|rs N|UT|aggh 32N|x1h 32N
  const size_t needBin = 4 * (512 + P + (size_t)3 * E + (size_t)3 * N + UT_W +
                              (size_t)32 * N + (size_t)32 * N);
  // csr: deg N|start N|dis N|rs N|bsum64|colS E|rec 2E|UT|aggh 32N|x1h 32N|xsh 32N
  const size_t needCSR = 4 * ((size_t)4 * N + 64 + (size_t)3 * E + UT_W +
                              (size_t)32 * N + (size_t)32 * N + (size_t)32 * N);

  unsigned *start = nullptr; float *dis = nullptr, *rsv = nullptr;
  int* colS = nullptr; uint2* rec = nullptr; float4* UT = nullptr;
  u16 *aggh = nullptr, *x0h = nullptr, *x1h = nullptr, *x2h = nullptr;
  bool ok = false;

  if (binOK && ws_size >= needBin) {
    unsigned* bCnt  = (unsigned*)d_ws;
    unsigned* bBase = bCnt + 256;
    unsigned* pairs = bBase + 256;
    colS  = (int*)(pairs + P);
    rec   = (uint2*)(colS + E);
    start = (unsigned*)(rec + E);
    dis   = (float*)(start + N);
    rsv   = dis + N;
    UT    = (float4*)(rsv + N);
    aggh  = (u16*)(UT + 2 * 33 * 64);
    x1h   = aggh + (size_t)64 * N;
    x0h   = (u16*)pairs;
    x2h   = (u16*)pairs;

    hipMemsetAsync(bCnt, 0, 256 * 4, stream);
    k_binA<<<(E + BIN_CHUNK - 1) / BIN_CHUNK, 1024, 0, stream>>>(row, col, bCnt, pairs, E, NB, capA);
    k_bscan<<<1, 256, 0, stream>>>(bCnt, bBase, NB);
    k_binB<<<NB, 512, 0, stream>>>(pairs, bCnt, bBase, colS, start, dis, N, capA);
    ok = true;
  } else if (ws_size >= needCSR) {
    unsigned* deg = (unsigned*)d_ws;
    start = deg + N;                 // becomes segment-END after k_build
    dis   = (float*)(start + N);
    rsv   = dis + N;
    unsigned* bsum = (unsigned*)(rsv + N);
    colS  = (int*)(bsum + 64);
    rec   = (uint2*)(colS + E);
    UT    = (float4*)(rec + E);
    aggh  = (u16*)(UT + 2 * 33 * 64);
    x1h   = aggh + (size_t)64 * N;
    u16* xsh = x1h + (size_t)64 * N;
    x0h = xsh; x2h = xsh;

    const int nB = (N + 2047) / 2048;
    hipMemsetAsync(deg, 0, (size_t)N * 4, stream);
    k_deg<<<1024, 256, 0, stream>>>(row, deg, E);
    k_dis<<<(N + 255) / 256, 256, 0, stream>>>(deg, dis, N);
    k_scan1<<<nB, 256, 0, stream>>>(deg, start, bsum, N);
    k_scan2<<<1, 64, 0, stream>>>(bsum, nB);
    k_scan3<<<(N + 255) / 256, 256, 0, stream>>>(start, bsum, N);
    k_build<<<1024, 256, 0, stream>>>(row, col, start, colS, E);
    ok = true;
  }

  if (!ok) return;

  k_wgt<<<(N + 15) / 16, 256, 0, stream>>>(colS, start, dis, rec, rsv, N);
  k_cast<<<1024, 256, 0, stream>>>((const float4*)x0, (ushort4*)x0h, N * 16);
  k_prep<<<17, 256, 0, stream>>>(W1, b1, Wr1, br1, W2, b2, Wr2, br2, UT);

  // layer 1
  k_spmm_rec<<<(N + 15) / 16, 256, 0, stream>>>(x0h, aggh, rec, start, dis, N);
  k_gemv<<<(N + 63) / 64, 256, 0, stream>>>(aggh, rsv, x0h, UT, x1h, N);

  // layer 2
  k_spmm_rec<<<(N + 15) / 16, 256, 0, stream>>>(x1h, aggh, rec, start, dis, N);
  k_gemv<<<(N + 63) / 64, 256, 0, stream>>>(aggh, rsv, x1h, UT + 33 * 64, x2h, N);

  // head
  k_final<<<(N + 63) / 64, 256, 0, stream>>>(x1h, x2h, Wl, bl, out, N);
}